// Round 2
// baseline (805.775 us; speedup 1.0000x reference)
//
#include <hip/hip_runtime.h>
#include <hip/hip_fp16.h>

// Pipeline (all fp16 MFMA, f32 accum):
//   ws: Wq_h[768x768] Wk_h[768x768] Wv_h[577x768] q_h[36928x768] k_h[36928x768]
//       v_h[36928x608] attn_h[36928x608]   (~197 MiB)
//   1) convert weights f32->fp16
//   2) q = b@Wq^T + bq          (A f32 on-the-fly convert)
//   3) k = e@Wk^T + bk
//   4) v = b@Wv^T + bv          (N=577 stored padded to 608 with zeros)
//   5) attn = tanh(q@k^T)       batched z=64, padded cols zeroed
//   6) out  = attn@v^T          batched, K=608 (pad cols are zeros), f32 out
// All GEMMs are NT: C[i,j] = sum_k A[i,k]*Bt[j,k], both row-major, contiguous K.

typedef _Float16 f16x8 __attribute__((ext_vector_type(8)));
typedef float f32x4 __attribute__((ext_vector_type(4)));

__global__ void cvt_kernel(const float* __restrict__ src, _Float16* __restrict__ dst, int n) {
    int i = blockIdx.x * blockDim.x + threadIdx.x;
    int stride = gridDim.x * blockDim.x;
    for (; i < n; i += stride) dst[i] = (_Float16)src[i];
}

// 128x128 tile, 4 waves (2x2 of 64x64), BK=32, MFMA 16x16x32 f16.
// A-frag lane l: row (l&15), k = 8*(l>>4)+j (contiguous 16B). B-frag same from Bt rows.
// C/D: col = lane&15, row = (lane>>4)*4 + r   [guide §3, m89/m91-verified]
template<bool A_F32, bool TANH, bool OUT_F16, bool BIAS>
__global__ __launch_bounds__(256)
void gemm_nt(const void* __restrict__ Ap, const _Float16* __restrict__ Bp,
             const float* __restrict__ bias, void* __restrict__ Cp,
             int M, int Nreal, int Nstore, int K,
             int lda, int ldb, int ldc,
             long long sA, long long sB, long long sC)
{
    __shared__ _Float16 As[128][40];  // +8 pad: ds_read_b128 spreads over banks
    __shared__ _Float16 Bs[128][40];

    const int z  = blockIdx.z;
    const int m0 = blockIdx.y * 128;
    const int n0 = blockIdx.x * 128;
    const int tid  = threadIdx.x;
    const int lane = tid & 63;
    const int wid  = tid >> 6;
    const int wm = wid >> 1, wn = wid & 1;

    const float*    Af = (const float*)Ap    + (size_t)z * sA;
    const _Float16* Ah = (const _Float16*)Ap + (size_t)z * sA;
    const _Float16* Bh = Bp + (size_t)z * sB;

    const f32x4 z4 = {0.f, 0.f, 0.f, 0.f};
    f32x4 acc[4][4];
#pragma unroll
    for (int i = 0; i < 4; ++i)
#pragma unroll
        for (int j = 0; j < 4; ++j) acc[i][j] = z4;

    for (int k0 = 0; k0 < K; k0 += 32) {
        __syncthreads();
#pragma unroll
        for (int i = 0; i < 2; ++i) {
            const int slot = tid + i * 256;         // 512 slots = 128 rows x 4 k-chunks(8)
            const int r  = slot >> 2;
            const int kc = (slot & 3) << 3;
            {   // A tile
                const int gr = m0 + r;
                f16x8 h;
#pragma unroll
                for (int j = 0; j < 8; ++j) h[j] = (_Float16)0.f;
                if (gr < M) {
                    if (A_F32) {
                        const float* p = Af + (size_t)gr * lda + k0 + kc;
                        float4 f0 = *(const float4*)p;
                        float4 f1 = *(const float4*)(p + 4);
                        h[0]=(_Float16)f0.x; h[1]=(_Float16)f0.y; h[2]=(_Float16)f0.z; h[3]=(_Float16)f0.w;
                        h[4]=(_Float16)f1.x; h[5]=(_Float16)f1.y; h[6]=(_Float16)f1.z; h[7]=(_Float16)f1.w;
                    } else {
                        h = *(const f16x8*)(Ah + (size_t)gr * lda + k0 + kc);
                    }
                }
                *(f16x8*)(&As[r][kc]) = h;
            }
            {   // B tile (rows are N-dim of output; zero-fill beyond Nreal)
                const int gr = n0 + r;
                f16x8 h;
#pragma unroll
                for (int j = 0; j < 8; ++j) h[j] = (_Float16)0.f;
                if (gr < Nreal) h = *(const f16x8*)(Bh + (size_t)gr * ldb + k0 + kc);
                *(f16x8*)(&Bs[r][kc]) = h;
            }
        }
        __syncthreads();

        const int koff = (lane >> 4) << 3;
        const int rr   = lane & 15;
        f16x8 a[4], b[4];
#pragma unroll
        for (int mi = 0; mi < 4; ++mi) a[mi] = *(const f16x8*)(&As[wm * 64 + mi * 16 + rr][koff]);
#pragma unroll
        for (int ni = 0; ni < 4; ++ni) b[ni] = *(const f16x8*)(&Bs[wn * 64 + ni * 16 + rr][koff]);
#pragma unroll
        for (int mi = 0; mi < 4; ++mi)
#pragma unroll
            for (int ni = 0; ni < 4; ++ni)
                acc[mi][ni] = __builtin_amdgcn_mfma_f32_16x16x32_f16(a[mi], b[ni], acc[mi][ni], 0, 0, 0);
    }

    // epilogue: bias -> tanh -> store (zero-fill padded cols [Nreal, Nstore))
    const int cr0 = (lane >> 4) << 2;
    const int cc  = lane & 15;
    float*    Cf = (float*)Cp    + (size_t)z * sC;
    _Float16* Ch = (_Float16*)Cp + (size_t)z * sC;
#pragma unroll
    for (int mi = 0; mi < 4; ++mi) {
#pragma unroll
        for (int ni = 0; ni < 4; ++ni) {
            const int gc = n0 + wn * 64 + ni * 16 + cc;
            if (gc >= Nstore) continue;
            const bool real = gc < Nreal;
            float bb = 0.f;
            if (BIAS) bb = real ? bias[gc] : 0.f;
#pragma unroll
            for (int r = 0; r < 4; ++r) {
                const int gr = m0 + wm * 64 + mi * 16 + cr0 + r;
                if (gr >= M) continue;
                float x = real ? (acc[mi][ni][r] + bb) : 0.f;
                if (TANH) x = tanhf(x);
                if (OUT_F16) Ch[(size_t)gr * ldc + gc] = (_Float16)x;
                else         Cf[(size_t)gr * ldc + gc] = x;
            }
        }
    }
}

extern "C" void kernel_launch(void* const* d_in, const int* in_sizes, int n_in,
                              void* d_out, int out_size, void* d_ws, size_t ws_size,
                              hipStream_t stream)
{
    const float* b  = (const float*)d_in[0];
    const float* e  = (const float*)d_in[1];
    const float* Wq = (const float*)d_in[2];
    const float* bq = (const float*)d_in[3];
    const float* Wk = (const float*)d_in[4];
    const float* bk = (const float*)d_in[5];
    const float* Wv = (const float*)d_in[6];
    const float* bv = (const float*)d_in[7];
    float* out = (float*)d_out;

    const int B = 64, T = 577, D = 768, S = 577;
    const int BT = B * T;     // 36928
    const int Sp = 608;       // S padded to multiple of 32

    _Float16* Wq_h = (_Float16*)d_ws;                     // 768*768
    _Float16* Wk_h = Wq_h + 768 * 768;                    // 768*768
    _Float16* Wv_h = Wk_h + 768 * 768;                    // 577*768
    _Float16* q_h  = Wv_h + 577 * 768;                    // BT*768
    _Float16* k_h  = q_h + (size_t)BT * 768;              // BT*768
    _Float16* v_h  = k_h + (size_t)BT * 768;              // BT*608
    _Float16* at_h = v_h + (size_t)BT * Sp;               // BT*608

    cvt_kernel<<<dim3(256), dim3(256), 0, stream>>>(Wq, Wq_h, 768 * 768);
    cvt_kernel<<<dim3(256), dim3(256), 0, stream>>>(Wk, Wk_h, 768 * 768);
    cvt_kernel<<<dim3(256), dim3(256), 0, stream>>>(Wv, Wv_h, 577 * 768);

    // q = b @ Wq^T + bq   [BT,768]
    gemm_nt<true, false, true, true><<<dim3(6, 289, 1), dim3(256), 0, stream>>>(
        b, Wq_h, bq, q_h, BT, D, D, D, D, D, D, 0, 0, 0);
    // k = e @ Wk^T + bk   [BT,768]
    gemm_nt<true, false, true, true><<<dim3(6, 289, 1), dim3(256), 0, stream>>>(
        e, Wk_h, bk, k_h, BT, D, D, D, D, D, D, 0, 0, 0);
    // v = b @ Wv^T + bv   [BT,608] (cols 577..607 zeroed)
    gemm_nt<true, false, true, true><<<dim3(5, 289, 1), dim3(256), 0, stream>>>(
        b, Wv_h, bv, v_h, BT, S, Sp, D, D, D, Sp, 0, 0, 0);
    // attn = tanh(q @ k^T)  batched [64][577,608], pad cols zeroed
    gemm_nt<false, true, true, false><<<dim3(5, 5, 64), dim3(256), 0, stream>>>(
        q_h, k_h, nullptr, at_h, T, S, Sp, D, D, D, Sp,
        (long long)T * D, (long long)S * D, (long long)T * Sp);
    // out = attn @ v^T   batched [64][577,577] f32, K=608 (pads are zeros)
    gemm_nt<false, false, false, false><<<dim3(5, 5, 64), dim3(256), 0, stream>>>(
        at_h, v_h, nullptr, out, T, T, T, Sp, Sp, Sp, T,
        (long long)T * Sp, (long long)T * Sp, (long long)T * T);
}

// Round 3
// 559.158 us; speedup vs baseline: 1.4411x; 1.4411x over previous
//
#include <hip/hip_runtime.h>
#include <hip/hip_fp16.h>

// Pipeline (all fp16 MFMA, f32 accum), m97-structure GEMMs:
//   cvt Wq,Wk,Wv ; cvt e -> slot1 ; k=e@Wk^T+bk -> slot2
//   cvt b -> slot1 (e dead) ; q=b@Wq^T+bq -> slot3 ; v=b@Wv^T+bv -> slot4 [BT,608]
//   attn=tanh(q@k^T) -> slot1 (b dead), batched z=64, pad cols zeroed
//   out=attn@v^T -> f32 d_out, batched, K=608 (pads zero)
// All GEMMs NT: C[i,j] = sum_k A[i,k]*Bt[j,k], both row-major, K contiguous.
// Staging: global_load_lds width=16, linear LDS [128][32] per operand (8 KB each).
// OOB rows clamped at staging (garbage only reaches discarded C rows/cols).

typedef _Float16 f16x8 __attribute__((ext_vector_type(8)));
typedef float f32x4 __attribute__((ext_vector_type(4)));

__global__ void cvt8_kernel(const float* __restrict__ src, _Float16* __restrict__ dst,
                            long long n8) {
    long long i = blockIdx.x * (long long)blockDim.x + threadIdx.x;
    const long long stride = gridDim.x * (long long)blockDim.x;
    for (; i < n8; i += stride) {
        const float4 f0 = ((const float4*)src)[2 * i];
        const float4 f1 = ((const float4*)src)[2 * i + 1];
        f16x8 h;
        h[0] = (_Float16)f0.x; h[1] = (_Float16)f0.y; h[2] = (_Float16)f0.z; h[3] = (_Float16)f0.w;
        h[4] = (_Float16)f1.x; h[5] = (_Float16)f1.y; h[6] = (_Float16)f1.z; h[7] = (_Float16)f1.w;
        ((f16x8*)dst)[i] = h;
    }
}

__device__ __forceinline__ void gload16(const _Float16* g, _Float16* l) {
    __builtin_amdgcn_global_load_lds(
        (const __attribute__((address_space(1))) unsigned int*)(g),
        (__attribute__((address_space(3))) unsigned int*)(l),
        16, 0, 0);
}

// 128x128 tile, 4 waves (2x2 of 64x64), BK=32, MFMA 16x16x32 f16.
// C/D: col = lane&15, row = (lane>>4)*4 + r   [guide §3, m89/m91-verified]
template<bool TANH, bool OUT_F16, bool BIAS, bool SWZ>
__global__ __launch_bounds__(256)
void gemm_nt_f16(const _Float16* __restrict__ A, const _Float16* __restrict__ Bt,
                 const float* __restrict__ bias, void* __restrict__ Cp,
                 int M, int Nreal, int Nstore, int K,
                 int lda, int ldb, int ldc, int nTileN,
                 long long sA, long long sB, long long sC)
{
    __shared__ __align__(16) _Float16 As[128 * 32];
    __shared__ __align__(16) _Float16 Bs[128 * 32];

    int bid = blockIdx.x;
    if (SWZ) {  // bijective XCD chunking (m204)
        const int nwg = gridDim.x;
        const int q8 = nwg >> 3, r8 = nwg & 7;
        const int xcd = bid & 7, loc = bid >> 3;
        bid = (xcd < r8 ? xcd * (q8 + 1) : r8 * (q8 + 1) + (xcd - r8) * q8) + loc;
    }
    const int tm = bid / nTileN, tn = bid - tm * nTileN;
    const int m0 = tm << 7, n0 = tn << 7;

    const int z = blockIdx.z;
    const _Float16* Az = A + (size_t)z * sA;
    const _Float16* Bz = Bt + (size_t)z * sB;

    const int tid = threadIdx.x;
    const int lane = tid & 63;
    const int wid = tid >> 6;
    const int wm = wid >> 1, wn = wid & 1;

    // staging: thread t owns 16B chunks t and t+256; chunk ch -> row ch>>2, halfcol (ch&3)*8
    const int r0 = tid >> 2, c0 = (tid & 3) << 3;
    const int rA0 = (m0 + r0      < M ? m0 + r0      : M - 1);
    const int rA1 = (m0 + r0 + 64 < M ? m0 + r0 + 64 : M - 1);
    const int rB0 = (n0 + r0      < Nreal ? n0 + r0      : Nreal - 1);
    const int rB1 = (n0 + r0 + 64 < Nreal ? n0 + r0 + 64 : Nreal - 1);
    const _Float16* pA0 = Az + (size_t)rA0 * lda + c0;
    const _Float16* pA1 = Az + (size_t)rA1 * lda + c0;
    const _Float16* pB0 = Bz + (size_t)rB0 * ldb + c0;
    const _Float16* pB1 = Bz + (size_t)rB1 * ldb + c0;
    _Float16* lA0 = As + tid * 8;
    _Float16* lA1 = As + (tid + 256) * 8;
    _Float16* lB0 = Bs + tid * 8;
    _Float16* lB1 = Bs + (tid + 256) * 8;

    // fragment LDS read base: lane l -> row (l&15), k-half (l>>4)*8
    const int rr = lane & 15;
    const int koff = (lane >> 4) << 3;
    const _Float16* fA = As + (wm * 64 + rr) * 32 + koff;
    const _Float16* fB = Bs + (wn * 64 + rr) * 32 + koff;

    const f32x4 z4 = {0.f, 0.f, 0.f, 0.f};
    f32x4 acc[4][4];
#pragma unroll
    for (int i = 0; i < 4; ++i)
#pragma unroll
        for (int j = 0; j < 4; ++j) acc[i][j] = z4;

    for (int k0 = 0; k0 < K; k0 += 32) {
        gload16(pA0 + k0, lA0);
        gload16(pA1 + k0, lA1);
        gload16(pB0 + k0, lB0);
        gload16(pB1 + k0, lB1);
        __syncthreads();   // vmcnt(0) drain + barrier: tile ready
        f16x8 a[4], b[4];
#pragma unroll
        for (int mi = 0; mi < 4; ++mi) a[mi] = *(const f16x8*)(fA + mi * 16 * 32);
#pragma unroll
        for (int ni = 0; ni < 4; ++ni) b[ni] = *(const f16x8*)(fB + ni * 16 * 32);
#pragma unroll
        for (int mi = 0; mi < 4; ++mi)
#pragma unroll
            for (int ni = 0; ni < 4; ++ni)
                acc[mi][ni] = __builtin_amdgcn_mfma_f32_16x16x32_f16(a[mi], b[ni], acc[mi][ni], 0, 0, 0);
        __syncthreads();   // all reads done before next overwrite
    }

    // epilogue: bias -> tanh -> store (zero padded cols [Nreal, Nstore))
    const int cr0 = (lane >> 4) << 2;
    const int cc = lane & 15;
    float*    Cf = (float*)Cp    + (size_t)z * sC;
    _Float16* Ch = (_Float16*)Cp + (size_t)z * sC;
#pragma unroll
    for (int mi = 0; mi < 4; ++mi) {
#pragma unroll
        for (int ni = 0; ni < 4; ++ni) {
            const int gc = n0 + wn * 64 + ni * 16 + cc;
            if (gc >= Nstore) continue;
            const bool real = gc < Nreal;
            float bb = 0.f;
            if (BIAS) bb = real ? bias[gc] : 0.f;
#pragma unroll
            for (int r = 0; r < 4; ++r) {
                const int gr = m0 + wm * 64 + mi * 16 + cr0 + r;
                if (gr >= M) continue;
                float x = real ? (acc[mi][ni][r] + bb) : 0.f;
                if (TANH) x = tanhf(x);
                if (OUT_F16) Ch[(size_t)gr * ldc + gc] = (_Float16)x;
                else         Cf[(size_t)gr * ldc + gc] = x;
            }
        }
    }
}

extern "C" void kernel_launch(void* const* d_in, const int* in_sizes, int n_in,
                              void* d_out, int out_size, void* d_ws, size_t ws_size,
                              hipStream_t stream)
{
    const float* b  = (const float*)d_in[0];
    const float* e  = (const float*)d_in[1];
    const float* Wq = (const float*)d_in[2];
    const float* bq = (const float*)d_in[3];
    const float* Wk = (const float*)d_in[4];
    const float* bk = (const float*)d_in[5];
    const float* Wv = (const float*)d_in[6];
    const float* bv = (const float*)d_in[7];
    float* out = (float*)d_out;

    const int BT = 36928, D = 768, T = 577, S = 577, Sp = 608;

    // ws layout (halfwords): weights 1.62M + 3x 28.36M slots + 1x 22.45M = ~218 MB
    _Float16* Wq_h  = (_Float16*)d_ws;
    _Float16* Wk_h  = Wq_h + 589824;
    _Float16* Wv_h  = Wk_h + 589824;
    _Float16* slot1 = Wv_h + 443136;                 // e_h -> b_h -> at_h
    _Float16* slot2 = slot1 + (size_t)BT * D;        // k_h
    _Float16* slot3 = slot2 + (size_t)BT * D;        // q_h
    _Float16* slot4 = slot3 + (size_t)BT * D;        // v_h [BT,608]

    cvt8_kernel<<<288, 256, 0, stream>>>(Wq, Wq_h, 73728);
    cvt8_kernel<<<288, 256, 0, stream>>>(Wk, Wk_h, 73728);
    cvt8_kernel<<<217, 256, 0, stream>>>(Wv, Wv_h, 55392);

    // e -> fp16
    cvt8_kernel<<<2048, 256, 0, stream>>>(e, slot1, 3545088);
    // k = e@Wk^T + bk   [BT,768]
    gemm_nt_f16<false, true, true, true><<<dim3(1734, 1, 1), 256, 0, stream>>>(
        slot1, Wk_h, bk, slot2, BT, D, D, D, D, D, D, 6, 0, 0, 0);
    // b -> fp16 (e_h dead)
    cvt8_kernel<<<2048, 256, 0, stream>>>(b, slot1, 3545088);
    // q = b@Wq^T + bq   [BT,768]
    gemm_nt_f16<false, true, true, true><<<dim3(1734, 1, 1), 256, 0, stream>>>(
        slot1, Wq_h, bq, slot3, BT, D, D, D, D, D, D, 6, 0, 0, 0);
    // v = b@Wv^T + bv   [BT,608] (cols 577..607 zeroed)
    gemm_nt_f16<false, true, true, true><<<dim3(1445, 1, 1), 256, 0, stream>>>(
        slot1, Wv_h, bv, slot4, BT, S, Sp, D, D, D, Sp, 5, 0, 0, 0);
    // attn = tanh(q@k^T) -> slot1 (b_h dead)  batched [64][577,608]
    gemm_nt_f16<true, true, false, false><<<dim3(25, 1, 64), 256, 0, stream>>>(
        slot3, slot2, nullptr, slot1, T, S, Sp, D, D, D, Sp, 5,
        (long long)T * D, (long long)T * D, (long long)T * Sp);
    // out = attn@v^T   batched [64][577,577] f32, K=608 (pads zero)
    gemm_nt_f16<false, false, false, false><<<dim3(25, 1, 64), 256, 0, stream>>>(
        slot1, slot4, nullptr, out, T, T, T, Sp, Sp, Sp, T, 5,
        (long long)T * Sp, (long long)T * Sp, (long long)T * T);
}

// Round 4
// 458.169 us; speedup vs baseline: 1.7587x; 1.2204x over previous
//
#include <hip/hip_runtime.h>
#include <hip/hip_fp16.h>

// Pipeline (all fp16 MFMA, f32 accum), 2-phase double-buffered GEMMs:
//   cvt Wq,Wk,Wv ; cvt e -> slot1 ; k=e@Wk^T+bk -> slot2
//   cvt b -> slot1 (e dead) ; q=b@Wq^T+bq -> slot3 ; v=b@Wv^T+bv -> slot4 [BT,608]
//   attn=tanh(q@k^T) -> slot1 (b dead), batched z=64, pad cols zeroed
//   out=attn@v^T -> f32 d_out, batched, K=608 (pads zero)
// All GEMMs NT: C[i,j] = sum_k A[i,k]*Bt[j,k], both row-major, K contiguous.
// Staging: global_load_lds width=16 into double-buffered linear LDS [128][32].
// Batched GEMMs use batch->XCD co-location: all 25 tiles of a batch on one XCD
// so its working set (<=3.5 MB) stays L2-resident.

typedef _Float16 f16x8 __attribute__((ext_vector_type(8)));
typedef float f32x4 __attribute__((ext_vector_type(4)));

__global__ void cvt8_kernel(const float* __restrict__ src, _Float16* __restrict__ dst,
                            long long n8) {
    long long i = blockIdx.x * (long long)blockDim.x + threadIdx.x;
    const long long stride = gridDim.x * (long long)blockDim.x;
    for (; i < n8; i += stride) {
        const float4 f0 = ((const float4*)src)[2 * i];
        const float4 f1 = ((const float4*)src)[2 * i + 1];
        f16x8 h;
        h[0] = (_Float16)f0.x; h[1] = (_Float16)f0.y; h[2] = (_Float16)f0.z; h[3] = (_Float16)f0.w;
        h[4] = (_Float16)f1.x; h[5] = (_Float16)f1.y; h[6] = (_Float16)f1.z; h[7] = (_Float16)f1.w;
        ((f16x8*)dst)[i] = h;
    }
}

__device__ __forceinline__ void gload16(const _Float16* g, _Float16* l) {
    __builtin_amdgcn_global_load_lds(
        (const __attribute__((address_space(1))) unsigned int*)(g),
        (__attribute__((address_space(3))) unsigned int*)(l),
        16, 0, 0);
}

// 128x128 tile, 4 waves (2x2 of 64x64), BK=32, MFMA 16x16x32 f16.
// C/D: col = lane&15, row = (lane>>4)*4 + r   [guide §3, m89/m91-verified]
// MODE 0: 1D grid over tiles, bijective XCD chunking (m204), z=0.
// MODE 1: batched; grid = 8*nTiles*(B/8); bid -> (xcd, z, tile) co-location.
template<bool TANH, bool OUT_F16, bool BIAS, int MODE>
__global__ __launch_bounds__(256)
void gemm_nt_f16(const _Float16* __restrict__ A, const _Float16* __restrict__ Bt,
                 const float* __restrict__ bias, void* __restrict__ Cp,
                 int M, int Nreal, int Nstore, int K,
                 int lda, int ldb, int ldc, int nTileN, int nTiles,
                 long long sA, long long sB, long long sC)
{
    __shared__ __align__(16) _Float16 lds[4 * 128 * 32];   // A0 B0 A1 B1 (32 KB)
    _Float16* As0 = lds;
    _Float16* Bs0 = lds + 4096;
    _Float16* As1 = lds + 8192;
    _Float16* Bs1 = lds + 12288;

    int bid = blockIdx.x;
    int z, tm, tn;
    if (MODE == 0) {
        const int nwg = gridDim.x;
        const int q8 = nwg >> 3, r8 = nwg & 7;
        const int xcd = bid & 7, loc = bid >> 3;
        bid = (xcd < r8 ? xcd * (q8 + 1) : r8 * (q8 + 1) + (xcd - r8) * q8) + loc;
        z = 0;
        tm = bid / nTileN; tn = bid - tm * nTileN;
    } else {
        const int xcd = bid & 7, idx = bid >> 3;
        const int g = idx / nTiles, tile = idx - g * nTiles;
        z = g * 8 + xcd;                      // batch z: all its tiles on one XCD
        tm = tile / nTileN; tn = tile - tm * nTileN;
    }
    const int m0 = tm << 7, n0 = tn << 7;

    const _Float16* Az = A + (size_t)z * sA;
    const _Float16* Bz = Bt + (size_t)z * sB;

    const int tid = threadIdx.x;
    const int lane = tid & 63;
    const int wid = tid >> 6;
    const int wm = wid >> 1, wn = wid & 1;

    // staging: thread t owns 16B chunks t and t+256; chunk ch -> row ch>>2, halfcol (ch&3)*8
    const int r0 = tid >> 2, c0 = (tid & 3) << 3;
    const int rA0 = (m0 + r0      < M ? m0 + r0      : M - 1);
    const int rA1 = (m0 + r0 + 64 < M ? m0 + r0 + 64 : M - 1);
    const int rB0 = (n0 + r0      < Nreal ? n0 + r0      : Nreal - 1);
    const int rB1 = (n0 + r0 + 64 < Nreal ? n0 + r0 + 64 : Nreal - 1);
    const _Float16* pA0 = Az + (size_t)rA0 * lda + c0;
    const _Float16* pA1 = Az + (size_t)rA1 * lda + c0;
    const _Float16* pB0 = Bz + (size_t)rB0 * ldb + c0;
    const _Float16* pB1 = Bz + (size_t)rB1 * ldb + c0;

    const int o0 = tid * 8, o1 = (tid + 256) * 8;

    // fragment LDS read offsets: lane l -> row (l&15), k-half (l>>4)*8
    const int rr = lane & 15;
    const int koff = (lane >> 4) << 3;
    const int fAo = (wm * 64 + rr) * 32 + koff;
    const int fBo = (wn * 64 + rr) * 32 + koff;

    const f32x4 z4 = {0.f, 0.f, 0.f, 0.f};
    f32x4 acc[4][4];
#pragma unroll
    for (int i = 0; i < 4; ++i)
#pragma unroll
        for (int j = 0; j < 4; ++j) acc[i][j] = z4;

    // prologue: stage tile 0
    gload16(pA0, As0 + o0); gload16(pA1, As0 + o1);
    gload16(pB0, Bs0 + o0); gload16(pB1, Bs0 + o1);
    __syncthreads();                       // vmcnt(0) drain: tile 0 ready

    _Float16 *cA = As0, *cB = Bs0, *nA = As1, *nB = Bs1;
    for (int k0 = 0; k0 < K; k0 += 32) {
        const int k1 = k0 + 32;
        if (k1 < K) {                      // prefetch next tile into alt buffer
            gload16(pA0 + k1, nA + o0); gload16(pA1 + k1, nA + o1);
            gload16(pB0 + k1, nB + o0); gload16(pB1 + k1, nB + o1);
        }
        f16x8 a[4], b[4];
#pragma unroll
        for (int mi = 0; mi < 4; ++mi) a[mi] = *(const f16x8*)(cA + fAo + mi * 16 * 32);
#pragma unroll
        for (int ni = 0; ni < 4; ++ni) b[ni] = *(const f16x8*)(cB + fBo + ni * 16 * 32);
#pragma unroll
        for (int mi = 0; mi < 4; ++mi)
#pragma unroll
            for (int ni = 0; ni < 4; ++ni)
                acc[mi][ni] = __builtin_amdgcn_mfma_f32_16x16x32_f16(a[mi], b[ni], acc[mi][ni], 0, 0, 0);
        __syncthreads();                   // drains prefetch vmcnt + guards overwrite
        _Float16* t;
        t = cA; cA = nA; nA = t;
        t = cB; cB = nB; nB = t;
    }

    // epilogue: bias -> tanh -> store (zero padded cols [Nreal, Nstore))
    const int cr0 = (lane >> 4) << 2;
    const int cc = lane & 15;
    float*    Cf = (float*)Cp    + (size_t)z * sC;
    _Float16* Ch = (_Float16*)Cp + (size_t)z * sC;
#pragma unroll
    for (int mi = 0; mi < 4; ++mi) {
#pragma unroll
        for (int ni = 0; ni < 4; ++ni) {
            const int gc = n0 + wn * 64 + ni * 16 + cc;
            if (gc >= Nstore) continue;
            const bool real = gc < Nreal;
            float bb = 0.f;
            if (BIAS) bb = real ? bias[gc] : 0.f;
#pragma unroll
            for (int r = 0; r < 4; ++r) {
                const int gr = m0 + wm * 64 + mi * 16 + cr0 + r;
                if (gr >= M) continue;
                float x = real ? (acc[mi][ni][r] + bb) : 0.f;
                if (TANH) x = tanhf(x);
                if (OUT_F16) Ch[(size_t)gr * ldc + gc] = (_Float16)x;
                else         Cf[(size_t)gr * ldc + gc] = x;
            }
        }
    }
}

extern "C" void kernel_launch(void* const* d_in, const int* in_sizes, int n_in,
                              void* d_out, int out_size, void* d_ws, size_t ws_size,
                              hipStream_t stream)
{
    const float* b  = (const float*)d_in[0];
    const float* e  = (const float*)d_in[1];
    const float* Wq = (const float*)d_in[2];
    const float* bq = (const float*)d_in[3];
    const float* Wk = (const float*)d_in[4];
    const float* bk = (const float*)d_in[5];
    const float* Wv = (const float*)d_in[6];
    const float* bv = (const float*)d_in[7];
    float* out = (float*)d_out;

    const int BT = 36928, D = 768, T = 577, S = 577, Sp = 608;

    // ws layout (halfwords): weights + 3x BT*768 slots + 1x BT*608 = ~218 MB
    _Float16* Wq_h  = (_Float16*)d_ws;
    _Float16* Wk_h  = Wq_h + 589824;
    _Float16* Wv_h  = Wk_h + 589824;
    _Float16* slot1 = Wv_h + 443136;                 // e_h -> b_h -> at_h
    _Float16* slot2 = slot1 + (size_t)BT * D;        // k_h
    _Float16* slot3 = slot2 + (size_t)BT * D;        // q_h
    _Float16* slot4 = slot3 + (size_t)BT * D;        // v_h [BT,608]

    cvt8_kernel<<<288, 256, 0, stream>>>(Wq, Wq_h, 73728);
    cvt8_kernel<<<288, 256, 0, stream>>>(Wk, Wk_h, 73728);
    cvt8_kernel<<<217, 256, 0, stream>>>(Wv, Wv_h, 55392);

    // e -> fp16
    cvt8_kernel<<<2048, 256, 0, stream>>>(e, slot1, 3545088);
    // k = e@Wk^T + bk   [BT,768]
    gemm_nt_f16<false, true, true, 0><<<dim3(1734, 1, 1), 256, 0, stream>>>(
        slot1, Wk_h, bk, slot2, BT, D, D, D, D, D, D, 6, 0, 0, 0, 0);
    // b -> fp16 (e_h dead)
    cvt8_kernel<<<2048, 256, 0, stream>>>(b, slot1, 3545088);
    // q = b@Wq^T + bq   [BT,768]
    gemm_nt_f16<false, true, true, 0><<<dim3(1734, 1, 1), 256, 0, stream>>>(
        slot1, Wq_h, bq, slot3, BT, D, D, D, D, D, D, 6, 0, 0, 0, 0);
    // v = b@Wv^T + bv   [BT,608] (cols 577..607 zeroed)
    gemm_nt_f16<false, true, true, 0><<<dim3(1445, 1, 1), 256, 0, stream>>>(
        slot1, Wv_h, bv, slot4, BT, S, Sp, D, D, D, Sp, 5, 0, 0, 0, 0);
    // attn = tanh(q@k^T) -> slot1 (b_h dead)  batched [64][577,608]
    gemm_nt_f16<true, true, false, 1><<<dim3(1600, 1, 1), 256, 0, stream>>>(
        slot3, slot2, nullptr, slot1, T, S, Sp, D, D, D, Sp, 5, 25,
        (long long)T * D, (long long)T * D, (long long)T * Sp);
    // out = attn@v^T   batched [64][577,577] f32, K=608 (pads zero)
    gemm_nt_f16<false, false, false, 1><<<dim3(1600, 1, 1), 256, 0, stream>>>(
        slot1, slot4, nullptr, out, T, T, T, Sp, Sp, Sp, T, 5, 25,
        (long long)T * Sp, (long long)T * Sp, (long long)T * T);
}